// Round 11
// baseline (512.393 us; speedup 1.0000x reference)
//
#include <hip/hip_runtime.h>
#include <math.h>

// Pipeline: bin points by truncated 4D-Morton key (64K buckets) -> process in
// Morton order. Main kernel: THREAD = POINT (sorted neighbors share grid
// cells, so a wave's 64 lane-loads hit few distinct lines), feat[16] lives in
// registers end-to-end, MLP per-thread with uniform LDS broadcast weights.
// LDS 5.3KB, launch_bounds(256,4) -> VGPR<=128, no spills, ~4 waves/EU.

#define NBUCKET 65536
#define SCAN_BLOCKS 64          // NBUCKET / 1024

__device__ __forceinline__ unsigned morton_key(int ty, int tx, int tz, int tw2) {
    // ty,tx: 6b; tz: 5b; tw2: 4b -> 21-bit Morton, LSB-first (w,z,x,y)
    unsigned k = 0;
    int pos = 0;
    #pragma unroll
    for (int b = 0; b < 6; ++b) {
        if (b < 4) { k |= ((unsigned)((tw2 >> b) & 1)) << pos; ++pos; }
        if (b < 5) { k |= ((unsigned)((tz  >> b) & 1)) << pos; ++pos; }
        k |= ((unsigned)((tx >> b) & 1)) << pos; ++pos;
        k |= ((unsigned)((ty >> b) & 1)) << pos; ++pos;
    }
    return k;
}

__device__ __forceinline__ unsigned point_key(const float4 xv) {
    // fast binning — performance only, never affects output values
    const float c0 = xv.x * (63.0f / (float)M_PI);
    const float c1 = (xv.y + (float)M_PI) * (63.0f / (float)(2.0 * M_PI));
    const float c2 = (xv.z - (float)(0.5 * M_PI)) * (31.0f / (float)(0.35 * M_PI));
    const float c3 = (xv.w + (float)(0.85 * M_PI)) * (31.0f / (float)(0.35 * M_PI));
    int tx = min(max((int)c0, 0), 63);
    int ty = min(max((int)c1, 0), 63);
    int tz = min(max((int)c2, 0), 31);
    int tw = min(max((int)c3, 0), 31);
    return morton_key(ty, tx, tz, tw >> 1) >> 5;   // 64K buckets, Morton order
}

__global__ __launch_bounds__(256) void k_hist(const float4* __restrict__ x,
                                              unsigned* __restrict__ hist, int N) {
    const int p = blockIdx.x * 256 + threadIdx.x;
    if (p >= N) return;
    atomicAdd(&hist[point_key(x[p])], 1u);
}

__global__ __launch_bounds__(1024) void k_scanA(unsigned* __restrict__ data,
                                                unsigned* __restrict__ partial) {
    __shared__ unsigned s[1024];
    const int t = threadIdx.x;
    const int base = blockIdx.x * 1024;
    const unsigned v = data[base + t];
    s[t] = v;
    __syncthreads();
    #pragma unroll
    for (int off = 1; off < 1024; off <<= 1) {
        const unsigned add = (t >= off) ? s[t - off] : 0u;
        __syncthreads();
        s[t] += add;
        __syncthreads();
    }
    data[base + t] = (t == 0) ? 0u : s[t - 1];           // exclusive
    if (t == 1023) partial[blockIdx.x] = s[1023];
}

// 64 partials: single-wave shfl scan
__global__ __launch_bounds__(64) void k_scanB(unsigned* __restrict__ partial) {
    const int t = threadIdx.x;
    const unsigned v = partial[t];
    unsigned s = v;
    #pragma unroll
    for (int off = 1; off < 64; off <<= 1) {
        const unsigned u = __shfl_up(s, off);
        if (t >= off) s += u;
    }
    partial[t] = s - v;                                   // exclusive
}

__global__ __launch_bounds__(1024) void k_scanC(unsigned* __restrict__ data,
                                                const unsigned* __restrict__ partial) {
    data[blockIdx.x * 1024 + threadIdx.x] += partial[blockIdx.x];
}

__global__ __launch_bounds__(256) void k_scatter(const float4* __restrict__ x,
                                                 unsigned* __restrict__ offsets,
                                                 float4* __restrict__ xs,
                                                 unsigned* __restrict__ rank, int N) {
    const int p = blockIdx.x * 256 + threadIdx.x;
    if (p >= N) return;
    const float4 xv = x[p];
    const unsigned slot = atomicAdd(&offsets[point_key(xv)], 1u);
    xs[slot] = xv;        // random 16B write (unavoidable for sorted reads)
    rank[p]  = slot;      // coalesced
}

// out[p] = tmp[rank[p]] : coalesced write, random read (tmp is L2/L3-resident)
__global__ __launch_bounds__(256) void k_unperm(const unsigned* __restrict__ rank,
                                                const float* __restrict__ tmp,
                                                float* __restrict__ out, int N) {
    const int p = blockIdx.x * 256 + threadIdx.x;
    if (p >= N) return;
    const unsigned i = rank[p];
    out[(size_t)p * 3 + 0] = tmp[(size_t)i * 3 + 0];
    out[(size_t)p * 3 + 1] = tmp[(size_t)i * 3 + 1];
    out[(size_t)p * 3 + 2] = tmp[(size_t)i * 3 + 2];
}

// ---------------- main compute: thread = point (round-3 bit-exact body) ----
template <bool SORTED>
__global__ __launch_bounds__(256, 4) void gridnet_main(
    const float4* __restrict__ xs,
    const float* __restrict__ grid,
    const float* __restrict__ w1, const float* __restrict__ b1,
    const float* __restrict__ w2, const float* __restrict__ b2,
    float* __restrict__ dst_buf, int N, int nblk)
{
    __shared__ float w1s[1024];      // [16][64]
    __shared__ float b1s[64];
    __shared__ float w2s[192];       // [64][3]
    __shared__ float b2s[4];

    const int t = threadIdx.x;
    for (int i = t; i < 1024; i += 256) w1s[i] = w1[i];
    if (t < 64)  b1s[t] = b1[t];
    if (t < 192) w2s[t] = w2[t];
    if (t < 3)   b2s[t] = b2[t];
    __syncthreads();

    int b = blockIdx.x;
    if ((nblk & 7) == 0)             // XCD-chunked order
        b = (blockIdx.x & 7) * (nblk >> 3) + (blockIdx.x >> 3);
    const int gp = b * 256 + t;
    if (gp >= N) return;

    const float4 xv = xs[gp];

    // BIT-EXACT coordinate path: (x - lo) / span * count, f64 consts cast to
    // f32, divide preserved (trunc decisions at cell edges are discrete).
    const float lo1 = (float)(-M_PI);
    const float sp0 = (float)(M_PI);
    const float sp1 = (float)(2.0 * M_PI);
    const float lo2 = (float)(0.5 * M_PI);
    const float sp2 = (float)(0.85 * M_PI - 0.5 * M_PI);
    const float lo3 = (float)(-0.85 * M_PI);
    const float sp3 = (float)(-0.5 * M_PI - (-0.85 * M_PI));

    const float c0 = (xv.x - 0.0f) / sp0 * 63.0f;
    const float c1 = (xv.y - lo1) / sp1 * 63.0f;
    const float c2 = (xv.z - lo2) / sp2 * 31.0f;
    const float c3 = (xv.w - lo3) / sp3 * 31.0f;

    const int tlx = (int)c0;
    const int tly = (int)c1;
    const int tlz = (int)c2;
    const int tlw = (int)c3;

    const float xf = c0 - (float)tlx;
    const float yf = c1 - (float)tly;
    const float zf = c2 - (float)tlz;
    const float wf = c3 - (float)tlw;

    const int brx = min(tlx + 1, 63);
    const int bry = min(tly + 1, 63);
    const int brz = min(tlz + 1, 31);
    const int brw = min(tlw + 1, 31);

    const float wx0 = 1.0f - xf, wx1 = xf;
    const float wy0 = 1.0f - yf, wy1 = yf;
    const float wz0 = 1.0f - zf, wz1 = zf;
    const float ww0 = 1.0f - wf, ww1 = wf;

    // reference quirk: iy==1 has (z0,w1)/(z1,w0) swapped
    float cw[2][2][2];
    cw[0][0][0] = wy0 * wz0 * ww0;
    cw[0][0][1] = wy0 * wz0 * ww1;
    cw[0][1][0] = wy0 * wz1 * ww0;
    cw[0][1][1] = wy0 * wz1 * ww1;
    cw[1][0][0] = wy1 * wz0 * ww0;
    cw[1][0][1] = wy1 * wz1 * ww0;   // swapped
    cw[1][1][0] = wy1 * wz0 * ww1;   // swapped
    cw[1][1][1] = wy1 * wz1 * ww1;

    const float wxv[2] = {wx0, wx1};
    const int axv[2] = {tlx, brx};
    const int ayv[2] = {tly, bry};
    const int azv[2] = {tlz, brz};
    const int awv[2] = {tlw, brw};

    float feat[16];
    #pragma unroll
    for (int f = 0; f < 16; ++f) feat[f] = 0.0f;

    #pragma unroll
    for (int iy = 0; iy < 2; ++iy) {
        #pragma unroll
        for (int ix = 0; ix < 2; ++ix) {
            const int base1 = (ayv[iy] * 64 + axv[ix]) * 32;
            const float wyx = wxv[ix];
            #pragma unroll
            for (int iz = 0; iz < 2; ++iz) {
                const int base0 = (base1 + azv[iz]) * 32;
                #pragma unroll
                for (int iw = 0; iw < 2; ++iw) {
                    const float w = wyx * cw[iy][iz][iw];
                    const float4* p4 = reinterpret_cast<const float4*>(
                        grid + (size_t)(base0 + awv[iw]) * 16);
                    const float4 v0 = p4[0];
                    const float4 v1 = p4[1];
                    const float4 v2 = p4[2];
                    const float4 v3 = p4[3];
                    feat[0]  += w * v0.x;  feat[1]  += w * v0.y;
                    feat[2]  += w * v0.z;  feat[3]  += w * v0.w;
                    feat[4]  += w * v1.x;  feat[5]  += w * v1.y;
                    feat[6]  += w * v1.z;  feat[7]  += w * v1.w;
                    feat[8]  += w * v2.x;  feat[9]  += w * v2.y;
                    feat[10] += w * v2.z;  feat[11] += w * v2.w;
                    feat[12] += w * v3.x;  feat[13] += w * v3.y;
                    feat[14] += w * v3.z;  feat[15] += w * v3.w;
                }
            }
        }
    }

    // MLP: h = leaky_relu(feat @ w1 + b1); out = sigmoid(h @ w2 + b2) * 255
    float o0 = b2s[0];
    float o1 = b2s[1];
    float o2 = b2s[2];

    #pragma unroll
    for (int j4 = 0; j4 < 16; ++j4) {
        float4 h = reinterpret_cast<const float4*>(b1s)[j4];
        #pragma unroll
        for (int i = 0; i < 16; ++i) {
            const float4 wv = reinterpret_cast<const float4*>(w1s)[i * 16 + j4];
            h.x += feat[i] * wv.x;
            h.y += feat[i] * wv.y;
            h.z += feat[i] * wv.z;
            h.w += feat[i] * wv.w;
        }
        const float hx = (h.x >= 0.0f) ? h.x : 0.01f * h.x;
        const float hy = (h.y >= 0.0f) ? h.y : 0.01f * h.y;
        const float hz = (h.z >= 0.0f) ? h.z : 0.01f * h.z;
        const float hw = (h.w >= 0.0f) ? h.w : 0.01f * h.w;
        const float* w2p = w2s + j4 * 12;
        o0 += hx * w2p[0] + hy * w2p[3] + hz * w2p[6] + hw * w2p[9];
        o1 += hx * w2p[1] + hy * w2p[4] + hz * w2p[7] + hw * w2p[10];
        o2 += hx * w2p[2] + hy * w2p[5] + hz * w2p[8] + hw * w2p[11];
    }

    float* dst = dst_buf + (size_t)gp * 3;   // SORTED: coalesced tmp write
    dst[0] = 255.0f / (1.0f + expf(-o0));
    dst[1] = 255.0f / (1.0f + expf(-o1));
    dst[2] = 255.0f / (1.0f + expf(-o2));
}

extern "C" void kernel_launch(void* const* d_in, const int* in_sizes, int n_in,
                              void* d_out, int out_size, void* d_ws, size_t ws_size,
                              hipStream_t stream) {
    const float* x    = (const float*)d_in[0];
    const float* grid = (const float*)d_in[1];
    const float* w1   = (const float*)d_in[2];
    const float* b1   = (const float*)d_in[3];
    const float* w2   = (const float*)d_in[4];
    const float* b2   = (const float*)d_in[5];
    float* out = (float*)d_out;

    const int N = in_sizes[0] / 4;               // x is [N,4]
    const int nblk = (N + 255) / 256;

    const size_t xs_bytes   = (size_t)N * 16;
    const size_t rank_bytes = (size_t)N * 4;
    const size_t tmp_bytes  = (size_t)N * 12;
    const size_t hist_bytes = (size_t)NBUCKET * 4;
    const size_t part_bytes = (size_t)SCAN_BLOCKS * 4;
    const size_t need = xs_bytes + rank_bytes + tmp_bytes + hist_bytes + part_bytes;

    if (ws_size >= need) {
        char* ws = (char*)d_ws;
        float4*   xs      = (float4*)ws;
        unsigned* rank    = (unsigned*)(ws + xs_bytes);
        float*    tmp     = (float*)   (ws + xs_bytes + rank_bytes);
        unsigned* hist    = (unsigned*)(ws + xs_bytes + rank_bytes + tmp_bytes);
        unsigned* partial = (unsigned*)(ws + xs_bytes + rank_bytes + tmp_bytes + hist_bytes);
        const float4* x4 = (const float4*)x;

        hipMemsetAsync(hist, 0, hist_bytes, stream);
        k_hist   <<<nblk, 256, 0, stream>>>(x4, hist, N);
        k_scanA  <<<SCAN_BLOCKS, 1024, 0, stream>>>(hist, partial);
        k_scanB  <<<1, 64, 0, stream>>>(partial);
        k_scanC  <<<SCAN_BLOCKS, 1024, 0, stream>>>(hist, partial);
        k_scatter<<<nblk, 256, 0, stream>>>(x4, hist, xs, rank, N);
        gridnet_main<true><<<nblk, 256, 0, stream>>>(
            xs, grid, w1, b1, w2, b2, tmp, N, nblk);
        k_unperm <<<nblk, 256, 0, stream>>>(rank, tmp, out, N);
    } else {
        gridnet_main<false><<<nblk, 256, 0, stream>>>(
            (const float4*)x, grid, w1, b1, w2, b2, out, N, nblk);
    }
}